// Round 3
// baseline (389.754 us; speedup 1.0000x reference)
//
#include <hip/hip_runtime.h>
#include <hip/hip_bf16.h>
#include <math.h>

// Problem constants (from reference): B=256, N=1024, H=256, K=5
#define BGRAPHS 256
#define NNODES  1024
#define HDIM    256
#define KSEL    5
#define NEG_SLOPE 0.01f

// ---------------------------------------------------------------------------
// Kernel 1: per-node max over H=256 f32 channels -> keys[b*N+n], masked to
// -inf for padded nodes. Each block covers 4 consecutive nodes: thread t
// loads one float4 (16B) -> 256*16B = 4 KiB = 4 rows, fully coalesced.
// Wave w (64 lanes * 16B = 1 KiB) owns exactly node (blk*4 + w).
// ---------------------------------------------------------------------------
__global__ __launch_bounds__(256) void node_max_kernel(
        const float* __restrict__ h,
        const int* __restrict__ n_nodes,
        float* __restrict__ keys) {
    const int t = threadIdx.x;
    const long long blk = blockIdx.x;                  // B*N/4 blocks
    const float4* __restrict__ h4 = (const float4*)h;  // 16B per thread
    float4 d = h4[blk * 256 + t];
    float m = fmaxf(fmaxf(d.x, d.y), fmaxf(d.z, d.w));
#pragma unroll
    for (int off = 32; off > 0; off >>= 1)
        m = fmaxf(m, __shfl_xor(m, off, 64));
    if ((t & 63) == 0) {
        int node = (int)(blk * 4 + (t >> 6));          // global node index
        int b  = node >> 10;                           // / N
        int nn = node & 1023;                          // % N
        keys[node] = (nn < n_nodes[b]) ? m : -INFINITY;
    }
}

// ---------------------------------------------------------------------------
// Kernel 2: one block (256 threads) per graph.
//   top-5 by (key desc, idx asc)  [jax.lax.top_k stable tie-break]
//   gather the 5 rows, rank-sort each ascending (jnp.sort)
//   logit_k = leaky_relu(dot(sorted_k, W1) + dot(q, W2)); softmax over K;
//   out = sum_k atten_k * sorted_k. Invalid rows (key==-inf) are zeroed but
//   STILL participate in the softmax (matches reference semantics; duplicate
//   -inf picks are benign because those rows are zeroed).
// ---------------------------------------------------------------------------
__global__ __launch_bounds__(256) void topk_attn_kernel(
        const float* __restrict__ h,
        const float* __restrict__ q,
        const float* __restrict__ W,    // [2H] flat: W1 = W[0:H], W2 = W[H:2H]
        const float* __restrict__ keys,
        float* __restrict__ out) {
    __shared__ float keys_s[NNODES];
    __shared__ float red_v[256];
    __shared__ int   red_i[256];
    __shared__ float sorted_s[KSEL][HDIM];
    __shared__ float vals_s[HDIM];
    __shared__ float dots[KSEL];
    __shared__ float atten[KSEL];
    __shared__ float cb_s;
    __shared__ int   top_idx[KSEL];
    __shared__ float top_val[KSEL];

    const int t = threadIdx.x;
    const int b = blockIdx.x;

    // ---- load this graph's keys into LDS (coalesced) ----
#pragma unroll
    for (int i = 0; i < 4; ++i)
        keys_s[t + 256 * i] = keys[b * NNODES + t + 256 * i];

    // ---- c_b = dot(q_b, W2) ----
    red_v[t] = q[b * HDIM + t] * W[HDIM + t];
    __syncthreads();
    for (int s = 128; s > 0; s >>= 1) {
        if (t < s) red_v[t] += red_v[t + s];
        __syncthreads();
    }
    if (t == 0) cb_s = red_v[0];
    __syncthreads();

    // ---- top-5: 5 x block argmax with (val desc, idx asc) ordering ----
    for (int k = 0; k < KSEL; ++k) {
        float bv = -INFINITY;
        int   bi = 0x7fffffff;
#pragma unroll
        for (int i = 0; i < 4; ++i) {
            int j = t * 4 + i;
            float v = keys_s[j];
            if (v > bv || (v == bv && j < bi)) { bv = v; bi = j; }
        }
        red_v[t] = bv;
        red_i[t] = bi;
        __syncthreads();
        for (int s = 128; s > 0; s >>= 1) {
            if (t < s) {
                float ov = red_v[t + s];
                int   oi = red_i[t + s];
                if (ov > red_v[t] || (ov == red_v[t] && oi < red_i[t])) {
                    red_v[t] = ov;
                    red_i[t] = oi;
                }
            }
            __syncthreads();
        }
        if (t == 0) {
            top_idx[k] = red_i[0];
            top_val[k] = red_v[0];
            keys_s[red_i[0]] = -INFINITY;   // exclude for next round
        }
        __syncthreads();
    }

    // ---- gather + rank-sort each selected row (ascending) ----
    for (int k = 0; k < KSEL; ++k) {
        int  sel   = top_idx[k];
        bool valid = (top_val[k] != -INFINITY);
        float v = 0.0f;
        if (valid)
            v = h[((long long)b * NNODES + sel) * HDIM + t];
        vals_s[t] = v;
        __syncthreads();
        int rank = 0;
        for (int j = 0; j < HDIM; ++j) {
            float vj = vals_s[j];                       // broadcast read, conflict-free
            rank += (vj < v) || (vj == v && j < t);     // total order -> bijection
        }
        sorted_s[k][rank] = v;
        __syncthreads();
    }

    // ---- logits: dot(sorted_k, W1) via block reduce ----
    float w1 = W[t];
    for (int k = 0; k < KSEL; ++k) {
        red_v[t] = sorted_s[k][t] * w1;
        __syncthreads();
        for (int s = 128; s > 0; s >>= 1) {
            if (t < s) red_v[t] += red_v[t + s];
            __syncthreads();
        }
        if (t == 0) dots[k] = red_v[0];
        __syncthreads();
    }

    // ---- leaky-relu + softmax over K (thread 0) ----
    if (t == 0) {
        float lg[KSEL];
        float mx = -INFINITY;
#pragma unroll
        for (int k = 0; k < KSEL; ++k) {
            float x = dots[k] + cb_s;        // invalid rows: dot==0 -> x=c_b
            lg[k] = (x > 0.0f) ? x : NEG_SLOPE * x;
            mx = fmaxf(mx, lg[k]);
        }
        float den = 0.0f;
#pragma unroll
        for (int k = 0; k < KSEL; ++k) { lg[k] = expf(lg[k] - mx); den += lg[k]; }
#pragma unroll
        for (int k = 0; k < KSEL; ++k) atten[k] = lg[k] / den;
    }
    __syncthreads();

    // ---- weighted sum, f32 store (reference output dtype is float32) ----
    float o = 0.0f;
#pragma unroll
    for (int k = 0; k < KSEL; ++k)
        o += atten[k] * sorted_s[k][t];

    out[b * HDIM + t] = o;
}

extern "C" void kernel_launch(void* const* d_in, const int* in_sizes, int n_in,
                              void* d_out, int out_size, void* d_ws, size_t ws_size,
                              hipStream_t stream) {
    // Inputs (setup_inputs order, reference dtypes): h [B,N,H] f32,
    // n_nodes [B] int32, attention_query [B,H] f32, W [1,2H] f32.
    // Output: [B,H] f32.
    const float* h  = (const float*)d_in[0];
    const int*   nn = (const int*)d_in[1];
    const float* q  = (const float*)d_in[2];
    const float* W  = (const float*)d_in[3];
    float*       out = (float*)d_out;

    float* keys = (float*)d_ws;   // B*N floats = 1 MiB, fully overwritten every call

    // Pass 1: per-node max (memory-bound: reads 256 MiB f32)
    node_max_kernel<<<(BGRAPHS * NNODES) / 4, 256, 0, stream>>>(h, nn, keys);
    // Pass 2: per-graph top-5 + sort + attention (tiny)
    topk_attn_kernel<<<BGRAPHS, 256, 0, stream>>>(h, q, W, keys, out);
}